// Round 2
// baseline (203.433 us; speedup 1.0000x reference)
//
#include <hip/hip_runtime.h>

#define BB 4
#define CC 64
#define HH 128
#define WW 128
#define DD 256
#define NBOX 100
#define MAXDET 10
#define TOPK 5
#define PIX 16
#define WSEG (WW / PIX)   // 8

#define SEG_OFF   0
#define MASK_OFF  (HH * WW * BB)                  // 65536
#define KEPT_OFF  (MASK_OFF + BB * HH * WW)       // 131072
#define VALID_OFF (KEPT_OFF + BB * MAXDET * 5)    // 131272

// ws layout (ints): [0..159] rects (B,10,4), [160..199] valid flags
// ws layout (floats): [200] seg0
#define WS_RECTS 0
#define WS_VALID 160
#define WS_SEG0  200

__global__ __launch_bounds__(128) void nms_kernel(const float* __restrict__ rb,
                                                  float* __restrict__ out,
                                                  int* __restrict__ wsI) {
    __shared__ float lb[NBOX * 5];
    __shared__ float area[NBOX];
    __shared__ float iou[NBOX * NBOX];
    __shared__ int   cand[NBOX];
    __shared__ float rv[128];
    __shared__ int   ri[128];
    __shared__ int   flag;
    __shared__ int   selIdx;
    __shared__ int   selHas;

    const int b = blockIdx.x;
    const int t = threadIdx.x;

    for (int k = t; k < NBOX * 5; k += 128) lb[k] = rb[b * NBOX * 5 + k];
    if (t == 0) flag = 0;
    __syncthreads();

    if (t < NBOX) {
        float x1 = lb[t * 5], y1 = lb[t * 5 + 1], x2 = lb[t * 5 + 2], y2 = lb[t * 5 + 3];
        area[t] = fmaxf(x2 - x1, 0.f) * fmaxf(y2 - y1, 0.f);
        if (lb[t * 5 + 4] > 0.2f) flag = 1;   // benign race, all write 1
    }
    __syncthreads();
    const int use_thres = flag;
    if (t < NBOX) cand[t] = use_thres ? (lb[t * 5 + 4] > 0.2f ? 1 : 0) : 1;

    for (int k = t; k < NBOX * NBOX; k += 128) {
        int i = k / NBOX, j = k % NBOX;
        float lx = fmaxf(lb[i * 5],     lb[j * 5]);
        float ly = fmaxf(lb[i * 5 + 1], lb[j * 5 + 1]);
        float rx = fminf(lb[i * 5 + 2], lb[j * 5 + 2]);
        float ry = fminf(lb[i * 5 + 3], lb[j * 5 + 3]);
        float iw = fmaxf(rx - lx, 0.f), ih = fmaxf(ry - ly, 0.f);
        float inter = iw * ih;
        iou[k] = inter / (area[i] + area[j] - inter + 1e-9f);
    }
    __syncthreads();

    for (int det = 0; det < MAXDET; ++det) {
        // argmax with lowest-index tie break (matches jnp.argmax, incl. all -inf -> 0)
        float v = (t < NBOX && cand[t]) ? lb[t * 5 + 4] : -INFINITY;
        rv[t] = v;
        ri[t] = t;
        __syncthreads();
        for (int off = 64; off > 0; off >>= 1) {
            if (t < off) {
                float v2 = rv[t + off]; int i2 = ri[t + off];
                if (v2 > rv[t] || (v2 == rv[t] && i2 < ri[t])) { rv[t] = v2; ri[t] = i2; }
            }
            __syncthreads();
        }
        if (t == 0) { selIdx = ri[0]; selHas = (rv[0] > -INFINITY) ? 1 : 0; }
        __syncthreads();
        const int idx = selIdx, has = selHas;

        if (has) {
            if (t < NBOX) { if (iou[idx * NBOX + t] > 0.4f) cand[t] = 0; }
            if (t == 0) cand[idx] = 0;
        }
        __syncthreads();

        if (t == 0) {
            float k0 = lb[idx * 5], k1 = lb[idx * 5 + 1], k2 = lb[idx * 5 + 2],
                  k3 = lb[idx * 5 + 3], k4 = lb[idx * 5 + 4];
            float* kp = out + KEPT_OFF + (b * MAXDET + det) * 5;
            kp[0] = k0; kp[1] = k1; kp[2] = k2; kp[3] = k3; kp[4] = k4;
            int vld = (has && (k2 - k0 >= 1.f) && (k3 - k1 >= 1.f) &&
                       (use_thres || det < TOPK)) ? 1 : 0;
            out[VALID_OFF + b * MAXDET + det] = vld ? 1.f : 0.f;
            int x1 = min(max((int)floorf(k0 + 0.5f), 0), WW);
            int y1 = min(max((int)floorf(k1 + 0.5f), 0), HH);
            int x2 = min(max((int)floorf(k2 + 0.5f), 0), WW);
            int y2 = min(max((int)floorf(k3 + 0.5f), 0), HH);
            int* rp = wsI + WS_RECTS + (b * MAXDET + det) * 4;
            rp[0] = x1; rp[1] = y1; rp[2] = x2; rp[3] = y2;
            wsI[WS_VALID + b * MAXDET + det] = vld;
        }
    }
}

__global__ __launch_bounds__(256) void seg0_kernel(const float* __restrict__ b1,
                                                   const float* __restrict__ W2,
                                                   const float* __restrict__ b2,
                                                   const float* __restrict__ W3,
                                                   const float* __restrict__ b3,
                                                   float* __restrict__ wsF) {
    __shared__ float h1s[DD];
    __shared__ float red[DD];
    const int t = threadIdx.x;
    h1s[t] = fmaxf(b1[t], 0.f);
    __syncthreads();
    float acc = b2[t];
    for (int i = 0; i < DD; ++i) acc += h1s[i] * W2[i * DD + t];
    red[t] = fmaxf(acc, 0.f) * W3[t];
    __syncthreads();
    for (int off = 128; off > 0; off >>= 1) {
        if (t < off) red[t] += red[t + off];
        __syncthreads();
    }
    if (t == 0) wsF[WS_SEG0] = red[0] + b3[0];
}

__global__ __launch_bounds__(256) void main_kernel(const float* __restrict__ x,
                                                   const float* __restrict__ Wsem,
                                                   const float* __restrict__ bsem,
                                                   const float* __restrict__ W1,
                                                   const float* __restrict__ b1,
                                                   const float* __restrict__ W2,
                                                   const float* __restrict__ b2,
                                                   const float* __restrict__ W3,
                                                   const float* __restrict__ b3,
                                                   const int* __restrict__ wsI,
                                                   const float* __restrict__ wsF,
                                                   float* __restrict__ out) {
    __shared__ float xs[CC][PIX];
    __shared__ float bufA[PIX][DD];
    __shared__ float bufB[PIX][DD];
    __shared__ int   insideS[PIX];
    __shared__ int   rects[MAXDET * 4];
    __shared__ int   vald[MAXDET];

    const int t  = threadIdx.x;
    const int bi = blockIdx.x;
    const int b   = bi >> 10;          // / (HH*WSEG) = /1024
    const int rem = bi & 1023;
    const int h   = rem >> 3;          // / WSEG
    const int w0  = (rem & 7) << 4;    // * PIX

    if (t < MAXDET * 4) rects[t] = wsI[WS_RECTS + b * MAXDET * 4 + t];
    if (t >= 64 && t < 64 + MAXDET) vald[t - 64] = wsI[WS_VALID + b * MAXDET + (t - 64)];
    __syncthreads();

    if (t < PIX) {
        const int w = w0 + t;
        int ins = 0;
        for (int d = 0; d < MAXDET; ++d) {
            if (vald[d] && w >= rects[d * 4] && w < rects[d * 4 + 2] &&
                h >= rects[d * 4 + 1] && h < rects[d * 4 + 3]) ins = 1;
        }
        insideS[t] = ins;
        out[MASK_OFF + b * (HH * WW) + h * WW + w] = ins ? 0.f : 1.f;
    }
    __syncthreads();

    int any = 0;
    for (int p = 0; p < PIX; ++p) any |= insideS[p];
    if (!any) {
        const float s0 = wsF[WS_SEG0];
        if (t < PIX) out[SEG_OFF + (h * WW + w0 + t) * BB + b] = s0;
        return;
    }

    // stage x[b, :, h, w0..w0+15] into LDS
    {
        const int c = t >> 2, q = t & 3;
        const float4 v = *reinterpret_cast<const float4*>(
            &x[((size_t)(b * CC + c)) * (HH * WW) + h * WW + w0 + q * 4]);
        xs[c][q * 4 + 0] = v.x; xs[c][q * 4 + 1] = v.y;
        xs[c][q * 4 + 2] = v.z; xs[c][q * 4 + 3] = v.w;
    }
    __syncthreads();

    float acc[PIX];

    // seman + mask -> words (bufA)
    {
        const float bs = bsem[t];
#pragma unroll
        for (int p = 0; p < PIX; ++p) acc[p] = bs;
        for (int c = 0; c < CC; ++c) {
            const float wv = Wsem[c * DD + t];
#pragma unroll
            for (int p = 0; p < PIX; ++p) acc[p] = fmaf(xs[c][p], wv, acc[p]);
        }
#pragma unroll
        for (int p = 0; p < PIX; ++p) bufA[p][t] = insideS[p] ? acc[p] : 0.f;
    }
    __syncthreads();

    // h1 = relu(words @ W1 + b1) -> bufB
    {
        const float bb = b1[t];
#pragma unroll
        for (int p = 0; p < PIX; ++p) acc[p] = bb;
        for (int i = 0; i < DD; ++i) {
            const float wv = W1[i * DD + t];
#pragma unroll
            for (int p = 0; p < PIX; ++p) acc[p] = fmaf(bufA[p][i], wv, acc[p]);
        }
#pragma unroll
        for (int p = 0; p < PIX; ++p) bufB[p][t] = fmaxf(acc[p], 0.f);
    }
    __syncthreads();

    // h2 = relu(h1 @ W2 + b2) -> bufA
    {
        const float bb = b2[t];
#pragma unroll
        for (int p = 0; p < PIX; ++p) acc[p] = bb;
        for (int i = 0; i < DD; ++i) {
            const float wv = W2[i * DD + t];
#pragma unroll
            for (int p = 0; p < PIX; ++p) acc[p] = fmaf(bufB[p][i], wv, acc[p]);
        }
#pragma unroll
        for (int p = 0; p < PIX; ++p) bufA[p][t] = fmaxf(acc[p], 0.f);
    }
    __syncthreads();

    // seg = h2 @ W3 + b3[0]
    {
        const int wid = t >> 6, lane = t & 63;
        for (int pp = 0; pp < 4; ++pp) {
            const int p = wid * 4 + pp;
            float v = 0.f;
#pragma unroll
            for (int k = 0; k < 4; ++k) {
                const int j = lane + 64 * k;
                v = fmaf(bufA[p][j], W3[j], v);
            }
            for (int off = 32; off > 0; off >>= 1) v += __shfl_down(v, off);
            if (lane == 0) out[SEG_OFF + (h * WW + w0 + p) * BB + b] = v + b3[0];
        }
    }
}

extern "C" void kernel_launch(void* const* d_in, const int* in_sizes, int n_in,
                              void* d_out, int out_size, void* d_ws, size_t ws_size,
                              hipStream_t stream) {
    const float* x    = (const float*)d_in[0];
    const float* rb   = (const float*)d_in[1];
    const float* Wsem = (const float*)d_in[2];
    const float* bsem = (const float*)d_in[3];
    const float* W1   = (const float*)d_in[4];
    const float* b1   = (const float*)d_in[5];
    const float* W2   = (const float*)d_in[6];
    const float* b2   = (const float*)d_in[7];
    const float* W3   = (const float*)d_in[8];
    const float* b3   = (const float*)d_in[9];
    float* out = (float*)d_out;
    int*   wsI = (int*)d_ws;
    float* wsF = (float*)d_ws;

    nms_kernel<<<BB, 128, 0, stream>>>(rb, out, wsI);
    seg0_kernel<<<1, 256, 0, stream>>>(b1, W2, b2, W3, b3, wsF);
    main_kernel<<<BB * HH * WSEG, 256, 0, stream>>>(x, Wsem, bsem, W1, b1, W2, b2,
                                                    W3, b3, wsI, wsF, out);
}

// Round 3
// 139.140 us; speedup vs baseline: 1.4621x; 1.4621x over previous
//
#include <hip/hip_runtime.h>

#define BB 4
#define CC 64
#define HH 128
#define WW 128
#define DD 256
#define NBOX 100
#define MAXDET 10
#define TOPK 5
#define PIX 16

// out layout (floats): seg (HW,B,1), mask (B,H,W), kept (B,10,5), valid (B,10)
#define SEG_OFF   0
#define MASK_OFF  (BB * HH * WW)
#define KEPT_OFF  (MASK_OFF + BB * HH * WW)
#define VALID_OFF (KEPT_OFF + BB * MAXDET * 5)

// ws layout (int32 indices)
#define WS_RECTS 0      // 160 ints: (B,10,4) rounded+clipped rects
#define WS_VALID 160    // 40 ints
#define WS_COUNT 200    // 1 int: worklist size (zeroed by prep_kernel)
#define WS_SEG0  204    // 1 float: MLP(0) constant
#define WS_LIST  256    // <=16384 ints: packed (b<<14)|(h<<7)|w records

// ---------------------------------------------------------------------------
// Kernel A: blocks 0..3 = single-wave NMS per batch (register-resident,
// shfl-reduce argmax, on-the-fly IoU, zero barriers in the scan);
// block 4 = seg0 = MLP(0) constant + zero the worklist counter.
// ---------------------------------------------------------------------------
__global__ __launch_bounds__(256) void prep_kernel(const float* __restrict__ rb,
                                                   const float* __restrict__ b1,
                                                   const float* __restrict__ W2,
                                                   const float* __restrict__ b2,
                                                   const float* __restrict__ W3,
                                                   const float* __restrict__ b3,
                                                   float* __restrict__ out,
                                                   int* __restrict__ wsI,
                                                   float* __restrict__ wsF) {
    const int bid = blockIdx.x;
    const int tid = threadIdx.x;

    if (bid < BB) {
        __shared__ float lb[NBOX * 5];
        for (int k = tid; k < NBOX * 5; k += 256) lb[k] = rb[bid * NBOX * 5 + k];
        __syncthreads();
        if (tid >= 64) return;          // wave 0 only from here (no barriers below)
        const int t = tid;

        const float b0x1 = lb[t*5], b0y1 = lb[t*5+1], b0x2 = lb[t*5+2],
                    b0y2 = lb[t*5+3], b0c = lb[t*5+4];
        const bool has1 = t < (NBOX - 64);
        const int  j1 = t + 64;
        float b1x1=0.f, b1y1=0.f, b1x2=0.f, b1y2=0.f, b1c=-INFINITY;
        if (has1) { b1x1=lb[j1*5]; b1y1=lb[j1*5+1]; b1x2=lb[j1*5+2];
                    b1y2=lb[j1*5+3]; b1c=lb[j1*5+4]; }
        const float a0 = fmaxf(b0x2-b0x1,0.f)*fmaxf(b0y2-b0y1,0.f);
        const float a1 = fmaxf(b1x2-b1x1,0.f)*fmaxf(b1y2-b1y1,0.f);

        unsigned long long bal = __ballot(b0c > 0.2f) | __ballot(has1 && (b1c > 0.2f));
        const bool use_thres = (bal != 0ULL);
        bool cand0 = use_thres ? (b0c > 0.2f) : true;
        bool cand1 = has1 && (use_thres ? (b1c > 0.2f) : true);

        for (int det = 0; det < MAXDET; ++det) {
            // argmax with lowest-index tie-break (matches jnp.argmax; all -inf -> 0)
            float v  = cand0 ? b0c : -INFINITY;
            int  idx = t;
            if (cand1 && b1c > v) { v = b1c; idx = j1; }
            for (int off = 1; off < 64; off <<= 1) {
                float v2 = __shfl_xor(v, off);
                int   i2 = __shfl_xor(idx, off);
                if (v2 > v || (v2 == v && i2 < idx)) { v = v2; idx = i2; }
            }
            const bool has = (v > -INFINITY);
            // selected box (idx uniform across wave; LDS broadcast read)
            const float sx1 = lb[idx*5], sy1 = lb[idx*5+1], sx2 = lb[idx*5+2],
                        sy2 = lb[idx*5+3], sc5 = lb[idx*5+4];
            if (has) {
                const float sa = fmaxf(sx2-sx1,0.f)*fmaxf(sy2-sy1,0.f);
                {
                    float lx=fmaxf(sx1,b0x1), ly=fmaxf(sy1,b0y1);
                    float rx=fminf(sx2,b0x2), ry=fminf(sy2,b0y2);
                    float inter=fmaxf(rx-lx,0.f)*fmaxf(ry-ly,0.f);
                    if (inter/(sa + a0 - inter + 1e-9f) > 0.4f) cand0 = false;
                }
                if (has1) {
                    float lx=fmaxf(sx1,b1x1), ly=fmaxf(sy1,b1y1);
                    float rx=fminf(sx2,b1x2), ry=fminf(sy2,b1y2);
                    float inter=fmaxf(rx-lx,0.f)*fmaxf(ry-ly,0.f);
                    if (inter/(sa + a1 - inter + 1e-9f) > 0.4f) cand1 = false;
                }
                if (idx == t)  cand0 = false;
                if (idx == j1) cand1 = false;
            }
            if (t == 0) {
                float* kp = out + KEPT_OFF + (bid*MAXDET + det)*5;
                kp[0]=sx1; kp[1]=sy1; kp[2]=sx2; kp[3]=sy2; kp[4]=sc5;
                const int vld = (has && (sx2-sx1 >= 1.f) && (sy2-sy1 >= 1.f) &&
                                 (use_thres || det < TOPK)) ? 1 : 0;
                out[VALID_OFF + bid*MAXDET + det] = vld ? 1.f : 0.f;
                int x1 = min(max((int)floorf(sx1+0.5f),0),WW);
                int y1 = min(max((int)floorf(sy1+0.5f),0),HH);
                int x2 = min(max((int)floorf(sx2+0.5f),0),WW);
                int y2 = min(max((int)floorf(sy2+0.5f),0),HH);
                int* rp = wsI + WS_RECTS + (bid*MAXDET+det)*4;
                rp[0]=x1; rp[1]=y1; rp[2]=x2; rp[3]=y2;
                wsI[WS_VALID + bid*MAXDET + det] = vld;
            }
        }
    } else {
        // seg0 = MLP applied to the all-zero word vector
        __shared__ float h1s[DD];
        __shared__ float red[DD];
        const int t = tid;
        if (t == 0) wsI[WS_COUNT] = 0;
        h1s[t] = fmaxf(b1[t], 0.f);
        __syncthreads();
        float acc = b2[t];
        for (int i = 0; i < DD; ++i) acc = fmaf(h1s[i], W2[i*DD + t], acc);
        red[t] = fmaxf(acc, 0.f) * W3[t];
        __syncthreads();
        for (int off = 128; off > 0; off >>= 1) {
            if (t < off) red[t] += red[t + off];
            __syncthreads();
        }
        if (t == 0) wsF[WS_SEG0] = red[0] + b3[0];
    }
}

// ---------------------------------------------------------------------------
// Kernel B: 16 blocks x 256 thr. Thread = one 16-px row segment. Computes
// inside bits, writes mask + default seg0 for all pixels, appends inside
// pixels to the compact worklist (block-scan + one atomicAdd per block).
// ---------------------------------------------------------------------------
__global__ __launch_bounds__(256) void mask_kernel(int* __restrict__ wsI,
                                                   const float* __restrict__ wsF,
                                                   float* __restrict__ out) {
    const int bi = blockIdx.x;        // 0..15
    const int t  = threadIdx.x;
    const int b  = bi >> 2, qs = bi & 3;

    __shared__ int rects[MAXDET * 4];
    __shared__ int vald[MAXDET];
    __shared__ unsigned int bitsS[256];
    __shared__ int sc[256];
    __shared__ int baseS;
    __shared__ float seg0S;

    if (t < MAXDET * 4) rects[t] = wsI[WS_RECTS + b * MAXDET * 4 + t];
    else if (t < MAXDET * 5) vald[t - MAXDET * 4] = wsI[WS_VALID + b * MAXDET + (t - MAXDET * 4)];
    if (t == 0) seg0S = wsF[WS_SEG0];
    __syncthreads();

    const int s  = qs * 256 + t;      // segment index within batch
    const int h  = s >> 3;
    const int w0 = (s & 7) << 4;
    unsigned int bits = 0;
    for (int d = 0; d < MAXDET; ++d) {
        if (vald[d] && h >= rects[d*4+1] && h < rects[d*4+3]) {
            const int lo = max(rects[d*4],   w0);
            const int hi = min(rects[d*4+2], w0 + PIX);
            if (lo < hi) bits |= ((1u << (hi - w0)) - (1u << (lo - w0)));
        }
    }
    bitsS[t] = bits;
    const int n = __popc(bits);
    sc[t] = n;
    __syncthreads();
    for (int off = 1; off < 256; off <<= 1) {     // inclusive scan
        const int v = (t >= off) ? sc[t - off] : 0;
        __syncthreads();
        sc[t] += v;
        __syncthreads();
    }
    if (t == 255) baseS = atomicAdd(wsI + WS_COUNT, sc[255]);
    __syncthreads();
    int pos = WS_LIST + baseS + sc[t] - n;
    unsigned int rb_ = bits;
    while (rb_) {
        const int bp = __ffs(rb_) - 1;
        rb_ &= rb_ - 1;
        wsI[pos++] = (b << 14) | (h << 7) | (w0 + bp);
    }

    // mask + default seg for this block's 4096 contiguous pixels
    const float s0 = seg0S;
    const int pixbase = qs * 4096;
    for (int k = 0; k < 16; ++k) {
        const int j = k * 256 + t;
        const int inside = (bitsS[j >> 4] >> (j & 15)) & 1;
        const int hw = pixbase + j;
        out[MASK_OFF + b * (HH * WW) + hw] = inside ? 0.f : 1.f;
        out[SEG_OFF + hw * BB + b] = s0;          // heavy px overwritten by mlp_kernel
    }
}

// ---------------------------------------------------------------------------
// Kernel C: MLP on packed inside pixels only. 16 px/block, thread = output
// channel. Unroll-4 weight prefetch + float4 LDS activation reads.
// ---------------------------------------------------------------------------
__global__ __launch_bounds__(256) void mlp_kernel(const float* __restrict__ x,
                                                  const float* __restrict__ Wsem,
                                                  const float* __restrict__ bsem,
                                                  const float* __restrict__ W1,
                                                  const float* __restrict__ b1,
                                                  const float* __restrict__ W2,
                                                  const float* __restrict__ b2,
                                                  const float* __restrict__ W3,
                                                  const float* __restrict__ b3,
                                                  const int* __restrict__ wsI,
                                                  float* __restrict__ out) {
    const int bi = blockIdx.x;
    const int t  = threadIdx.x;
    const int cnt = wsI[WS_COUNT];
    if (bi * PIX >= cnt) return;

    __shared__ int   recs[PIX];
    __shared__ float xs[PIX][72];      // padded: 288B rows, 16B-aligned float4 reads
    __shared__ float bufA[PIX][DD];
    __shared__ float bufB[PIX][DD];

    if (t < PIX) {
        const int id = bi * PIX + t;
        recs[t] = (id < cnt) ? wsI[WS_LIST + id] : -1;
    }
    __syncthreads();

    // stage x[b, :, h, w] for the 16 listed pixels (lane group g loads 4 channels)
    {
        const int g = t >> 4, p = t & 15;
        int rec = recs[p]; if (rec < 0) rec = recs[0];
        const int b = rec >> 14, hw = rec & 16383;
        const float* xp = x + ((size_t)b * CC) * (HH * WW) + hw;
        xs[p][g]      = xp[(size_t)(g)      * (HH * WW)];
        xs[p][g + 16] = xp[(size_t)(g + 16) * (HH * WW)];
        xs[p][g + 32] = xp[(size_t)(g + 32) * (HH * WW)];
        xs[p][g + 48] = xp[(size_t)(g + 48) * (HH * WW)];
    }
    __syncthreads();

    float acc[PIX];

    // words = x @ Wsem + bsem  (all listed px are inside -> no masking)
    {
        const float bs = bsem[t];
#pragma unroll
        for (int p = 0; p < PIX; ++p) acc[p] = bs;
        for (int c = 0; c < CC; c += 4) {
            const float w0 = Wsem[(c+0)*DD + t];
            const float w1 = Wsem[(c+1)*DD + t];
            const float w2 = Wsem[(c+2)*DD + t];
            const float w3 = Wsem[(c+3)*DD + t];
#pragma unroll
            for (int p = 0; p < PIX; ++p) {
                const float4 a = *reinterpret_cast<const float4*>(&xs[p][c]);
                acc[p] = fmaf(a.x, w0, acc[p]);
                acc[p] = fmaf(a.y, w1, acc[p]);
                acc[p] = fmaf(a.z, w2, acc[p]);
                acc[p] = fmaf(a.w, w3, acc[p]);
            }
        }
#pragma unroll
        for (int p = 0; p < PIX; ++p) bufA[p][t] = acc[p];
    }
    __syncthreads();

    // h1 = relu(words @ W1 + b1)
    {
        const float bbv = b1[t];
#pragma unroll
        for (int p = 0; p < PIX; ++p) acc[p] = bbv;
        for (int i = 0; i < DD; i += 4) {
            const float w0 = W1[(i+0)*DD + t];
            const float w1 = W1[(i+1)*DD + t];
            const float w2 = W1[(i+2)*DD + t];
            const float w3 = W1[(i+3)*DD + t];
#pragma unroll
            for (int p = 0; p < PIX; ++p) {
                const float4 a = *reinterpret_cast<const float4*>(&bufA[p][i]);
                acc[p] = fmaf(a.x, w0, acc[p]);
                acc[p] = fmaf(a.y, w1, acc[p]);
                acc[p] = fmaf(a.z, w2, acc[p]);
                acc[p] = fmaf(a.w, w3, acc[p]);
            }
        }
#pragma unroll
        for (int p = 0; p < PIX; ++p) bufB[p][t] = fmaxf(acc[p], 0.f);
    }
    __syncthreads();

    // h2 = relu(h1 @ W2 + b2)
    {
        const float bbv = b2[t];
#pragma unroll
        for (int p = 0; p < PIX; ++p) acc[p] = bbv;
        for (int i = 0; i < DD; i += 4) {
            const float w0 = W2[(i+0)*DD + t];
            const float w1 = W2[(i+1)*DD + t];
            const float w2 = W2[(i+2)*DD + t];
            const float w3 = W2[(i+3)*DD + t];
#pragma unroll
            for (int p = 0; p < PIX; ++p) {
                const float4 a = *reinterpret_cast<const float4*>(&bufB[p][i]);
                acc[p] = fmaf(a.x, w0, acc[p]);
                acc[p] = fmaf(a.y, w1, acc[p]);
                acc[p] = fmaf(a.z, w2, acc[p]);
                acc[p] = fmaf(a.w, w3, acc[p]);
            }
        }
#pragma unroll
        for (int p = 0; p < PIX; ++p) bufA[p][t] = fmaxf(acc[p], 0.f);
    }
    __syncthreads();

    // seg = h2 @ W3 + b3[0]; scattered per-pixel store
    {
        const int wid = t >> 6, lane = t & 63;
#pragma unroll
        for (int pp = 0; pp < 4; ++pp) {
            const int p = wid * 4 + pp;
            float v = 0.f;
#pragma unroll
            for (int k = 0; k < 4; ++k) {
                const int j = lane + 64 * k;
                v = fmaf(bufA[p][j], W3[j], v);
            }
            for (int off = 32; off > 0; off >>= 1) v += __shfl_down(v, off);
            if (lane == 0) {
                const int rec = recs[p];
                if (rec >= 0) {
                    const int b = rec >> 14, hw = rec & 16383;
                    out[SEG_OFF + hw * BB + b] = v + b3[0];
                }
            }
        }
    }
}

extern "C" void kernel_launch(void* const* d_in, const int* in_sizes, int n_in,
                              void* d_out, int out_size, void* d_ws, size_t ws_size,
                              hipStream_t stream) {
    const float* x    = (const float*)d_in[0];
    const float* rb   = (const float*)d_in[1];
    const float* Wsem = (const float*)d_in[2];
    const float* bsem = (const float*)d_in[3];
    const float* W1   = (const float*)d_in[4];
    const float* b1   = (const float*)d_in[5];
    const float* W2   = (const float*)d_in[6];
    const float* b2   = (const float*)d_in[7];
    const float* W3   = (const float*)d_in[8];
    const float* b3   = (const float*)d_in[9];
    float* out = (float*)d_out;
    int*   wsI = (int*)d_ws;
    float* wsF = (float*)d_ws;

    prep_kernel<<<BB + 1, 256, 0, stream>>>(rb, b1, W2, b2, W3, b3, out, wsI, wsF);
    mask_kernel<<<16, 256, 0, stream>>>(wsI, wsF, out);
    // worst case inside px: 4 batches * 10 boxes * 17*17 = 11560 -> 723 blocks; 1024 is safe
    mlp_kernel<<<1024, 256, 0, stream>>>(x, Wsem, bsem, W1, b1, W2, b2, W3, b3, wsI, out);
}

// Round 4
// 105.673 us; speedup vs baseline: 1.9251x; 1.3167x over previous
//
#include <hip/hip_runtime.h>

typedef __attribute__((ext_vector_type(8))) short bf16x8;
typedef __attribute__((ext_vector_type(4))) float f32x4;

#define BB 4
#define CCH 64
#define HH 128
#define WW 128
#define DD 256
#define NBOX 100
#define MAXDET 10
#define TOPK 5

// out layout (floats): seg (HW,B,1), mask (B,H,W), kept (B,10,5), valid (B,10)
#define SEG_OFF   0
#define MASK_OFF  (BB * HH * WW)
#define KEPT_OFF  (MASK_OFF + BB * HH * WW)
#define VALID_OFF (KEPT_OFF + BB * MAXDET * 5)

// ws layout: int indices
#define WS_CNTB 0                     // 4 ints: per-batch worklist counts
#define WS_SEG0 8                     // 1 float
#define WS_BITS 16                    // 4096 ints: per-16px-segment inside bits
#define WS_LIST (WS_BITS + 4096)      // 4*4096 ints: per-batch hw lists
// bf16 shuffled weights at byte offset 128K (needs ws_size >= 426KB)
#define WB_BYTE_OFF 131072
#define WB_SEM 0                      // 32 chunks  (K=64 : 4w*4nt*2kk)
#define WB_W1  (32 * 512)             // 128 chunks (K=256: 4w*4nt*8kk)
#define WB_W2  (160 * 512)            // 128 chunks

__device__ __forceinline__ unsigned short f2bf(float f) {
    unsigned u = __float_as_uint(f);
    u = (u + 0x7FFFu + ((u >> 16) & 1u)) >> 16;
    return (unsigned short)u;
}
__device__ __forceinline__ float bf2f(unsigned short s) {
    return __uint_as_float(((unsigned)s) << 16);
}

// ---------------------------------------------------------------------------
// K1: blocks 0..3 = NMS (wave0) + rasterize (mask, bits, worklist) per batch;
//     block 4 = seg0 constant; blocks 5..76 = weight bf16 shuffle (4 chunks ea)
// ---------------------------------------------------------------------------
__global__ __launch_bounds__(256) void k1_kernel(
    const float* __restrict__ rb,
    const float* __restrict__ Wsem, const float* __restrict__ W1,
    const float* __restrict__ W2,
    const float* __restrict__ b1,   const float* __restrict__ b2,
    const float* __restrict__ W3,   const float* __restrict__ b3,
    float* __restrict__ out, int* __restrict__ wsI,
    float* __restrict__ wsF, short* __restrict__ wb)
{
    const int bid = blockIdx.x;
    const int t   = threadIdx.x;

    if (bid < BB) {
        __shared__ float lb[NBOX * 5];
        __shared__ int   rectsS[MAXDET * 4];
        __shared__ int   valdS[MAXDET];
        __shared__ int   sc[256];

        for (int k = t; k < NBOX * 5; k += 256) lb[k] = rb[bid * NBOX * 5 + k];
        __syncthreads();

        if (t < 64) {   // single-wave NMS, zero barriers inside
            const float b0x1 = lb[t*5], b0y1 = lb[t*5+1], b0x2 = lb[t*5+2],
                        b0y2 = lb[t*5+3], b0c = lb[t*5+4];
            const bool has1 = t < (NBOX - 64);
            const int  j1 = t + 64;
            float c1x1=0.f, c1y1=0.f, c1x2=0.f, c1y2=0.f, c1c=-INFINITY;
            if (has1) { c1x1=lb[j1*5]; c1y1=lb[j1*5+1]; c1x2=lb[j1*5+2];
                        c1y2=lb[j1*5+3]; c1c=lb[j1*5+4]; }
            const float a0 = fmaxf(b0x2-b0x1,0.f)*fmaxf(b0y2-b0y1,0.f);
            const float a1 = fmaxf(c1x2-c1x1,0.f)*fmaxf(c1y2-c1y1,0.f);

            unsigned long long bal = __ballot(b0c > 0.2f) | __ballot(has1 && (c1c > 0.2f));
            const bool use_thres = (bal != 0ULL);
            bool cand0 = use_thres ? (b0c > 0.2f) : true;
            bool cand1 = has1 && (use_thres ? (c1c > 0.2f) : true);

            for (int det = 0; det < MAXDET; ++det) {
                float v  = cand0 ? b0c : -INFINITY;
                int  idx = t;
                if (cand1 && c1c > v) { v = c1c; idx = j1; }
                for (int off = 1; off < 64; off <<= 1) {
                    float v2 = __shfl_xor(v, off);
                    int   i2 = __shfl_xor(idx, off);
                    if (v2 > v || (v2 == v && i2 < idx)) { v = v2; idx = i2; }
                }
                const bool has = (v > -INFINITY);
                const float sx1 = lb[idx*5], sy1 = lb[idx*5+1], sx2 = lb[idx*5+2],
                            sy2 = lb[idx*5+3], sc5 = lb[idx*5+4];
                if (has) {
                    const float sa = fmaxf(sx2-sx1,0.f)*fmaxf(sy2-sy1,0.f);
                    {
                        float lx=fmaxf(sx1,b0x1), ly=fmaxf(sy1,b0y1);
                        float rx=fminf(sx2,b0x2), ry=fminf(sy2,b0y2);
                        float inter=fmaxf(rx-lx,0.f)*fmaxf(ry-ly,0.f);
                        if (inter/(sa + a0 - inter + 1e-9f) > 0.4f) cand0 = false;
                    }
                    if (has1) {
                        float lx=fmaxf(sx1,c1x1), ly=fmaxf(sy1,c1y1);
                        float rx=fminf(sx2,c1x2), ry=fminf(sy2,c1y2);
                        float inter=fmaxf(rx-lx,0.f)*fmaxf(ry-ly,0.f);
                        if (inter/(sa + a1 - inter + 1e-9f) > 0.4f) cand1 = false;
                    }
                    if (idx == t)  cand0 = false;
                    if (idx == j1) cand1 = false;
                }
                if (t == 0) {
                    float* kp = out + KEPT_OFF + (bid*MAXDET + det)*5;
                    kp[0]=sx1; kp[1]=sy1; kp[2]=sx2; kp[3]=sy2; kp[4]=sc5;
                    const int vld = (has && (sx2-sx1 >= 1.f) && (sy2-sy1 >= 1.f) &&
                                     (use_thres || det < TOPK)) ? 1 : 0;
                    out[VALID_OFF + bid*MAXDET + det] = vld ? 1.f : 0.f;
                    int x1 = min(max((int)floorf(sx1+0.5f),0),WW);
                    int y1 = min(max((int)floorf(sy1+0.5f),0),HH);
                    int x2 = min(max((int)floorf(sx2+0.5f),0),WW);
                    int y2 = min(max((int)floorf(sy2+0.5f),0),HH);
                    rectsS[det*4]=x1; rectsS[det*4+1]=y1;
                    rectsS[det*4+2]=x2; rectsS[det*4+3]=y2;
                    valdS[det] = vld;
                }
            }
        }
        __syncthreads();

        // rasterize: thread t owns segments s = t*4 .. t*4+3 (64 consecutive px)
        int myBits[4];
        int n = 0;
        #pragma unroll
        for (int k = 0; k < 4; ++k) {
            const int s = t*4 + k;
            const int h = s >> 3, w0 = (s & 7) << 4;
            unsigned bits = 0;
            for (int d = 0; d < MAXDET; ++d) {
                if (valdS[d] && h >= rectsS[d*4+1] && h < rectsS[d*4+3]) {
                    const int lo = max(rectsS[d*4],   w0);
                    const int hi = min(rectsS[d*4+2], w0 + 16);
                    if (lo < hi) bits |= ((1u << (hi - w0)) - (1u << (lo - w0)));
                }
            }
            myBits[k] = (int)bits;
            n += __popc(bits);
            wsI[WS_BITS + bid*1024 + s] = (int)bits;
            float* mp = out + MASK_OFF + bid*(HH*WW) + s*16;
            #pragma unroll
            for (int q = 0; q < 4; ++q) {
                float4 v;
                v.x = ((bits >> (q*4+0)) & 1) ? 0.f : 1.f;
                v.y = ((bits >> (q*4+1)) & 1) ? 0.f : 1.f;
                v.z = ((bits >> (q*4+2)) & 1) ? 0.f : 1.f;
                v.w = ((bits >> (q*4+3)) & 1) ? 0.f : 1.f;
                *reinterpret_cast<float4*>(mp + q*4) = v;
            }
        }
        sc[t] = n;
        __syncthreads();
        for (int off = 1; off < 256; off <<= 1) {
            const int v = (t >= off) ? sc[t - off] : 0;
            __syncthreads();
            sc[t] += v;
            __syncthreads();
        }
        if (t == 255) wsI[WS_CNTB + bid] = sc[255];
        int pos = sc[t] - n;
        #pragma unroll
        for (int k = 0; k < 4; ++k) {
            unsigned bitsr = (unsigned)myBits[k];
            const int s = t*4 + k;
            while (bitsr) {
                const int bp = __ffs(bitsr) - 1;
                bitsr &= bitsr - 1;
                wsI[WS_LIST + bid*4096 + pos++] = s*16 + bp;
            }
        }
    } else if (bid == BB) {
        // seg0 = MLP(0)
        __shared__ float h1s[DD];
        __shared__ float red[DD];
        h1s[t] = fmaxf(b1[t], 0.f);
        __syncthreads();
        float acc = b2[t];
        for (int i = 0; i < DD; ++i) acc = fmaf(h1s[i], W2[i*DD + t], acc);
        red[t] = fmaxf(acc, 0.f) * W3[t];
        __syncthreads();
        for (int off = 128; off > 0; off >>= 1) {
            if (t < off) red[t] += red[t + off];
            __syncthreads();
        }
        if (t == 0) wsF[WS_SEG0] = red[0] + b3[0];
    } else {
        // weight shuffle into B-fragment chunk order:
        // chunk[l*8+j] = W[kk*32 + (l>>4)*8 + j][w*64 + nt*16 + (l&15)]
        const int g = (bid - BB - 1) * 4 + (t >> 6);   // 0..287
        const int l = t & 63;
        const float* src; int KK32, cp, sbase;
        if (g < 32)       { src = Wsem; KK32 = 2; cp = g;       sbase = WB_SEM; }
        else if (g < 160) { src = W1;   KK32 = 8; cp = g - 32;  sbase = WB_W1; }
        else              { src = W2;   KK32 = 8; cp = g - 160; sbase = WB_W2; }
        const int wq  = cp / (4 * KK32);
        const int rem = cp % (4 * KK32);
        const int nt = rem / KK32, kk = rem % KK32;
        const int k0 = kk*32 + (l >> 4)*8;
        const int nn = wq*64 + nt*16 + (l & 15);
        unsigned short h[8];
        #pragma unroll
        for (int j = 0; j < 8; ++j) h[j] = f2bf(src[(size_t)(k0 + j) * DD + nn]);
        int4 v;
        v.x = (int)((unsigned)h[0] | ((unsigned)h[1] << 16));
        v.y = (int)((unsigned)h[2] | ((unsigned)h[3] << 16));
        v.z = (int)((unsigned)h[4] | ((unsigned)h[5] << 16));
        v.w = (int)((unsigned)h[6] | ((unsigned)h[7] << 16));
        *reinterpret_cast<int4*>(wb + sbase + (size_t)cp*512 + l*8) = v;
    }
}

// ---------------------------------------------------------------------------
// K2: blocks [0,1024) = MFMA MLP on 16 worklist px (batch = bi>>8);
//     blocks [1024,1280) = seg0 fill for outside px (bit-guarded, race-free)
// ---------------------------------------------------------------------------
__global__ __launch_bounds__(256) void k2_kernel(
    const float* __restrict__ x,
    const float* __restrict__ bsem, const float* __restrict__ b1,
    const float* __restrict__ b2,   const float* __restrict__ W3,
    const float* __restrict__ b3,
    const int* __restrict__ wsI, const float* __restrict__ wsF,
    const short* __restrict__ wb, float* __restrict__ out)
{
    const int bi = blockIdx.x;
    const int t  = threadIdx.x;

    if (bi >= 1024) {
        const int px = (bi - 1024) * 256 + t;       // covers all 65536 px
        const int b = px >> 14, hw = px & 16383;
        const unsigned bits = (unsigned)wsI[WS_BITS + b*1024 + (hw >> 4)];
        if (!((bits >> (hw & 15)) & 1)) out[SEG_OFF + hw*BB + b] = wsF[WS_SEG0];
        return;
    }

    const int b    = bi >> 8;
    const int base = (bi & 255) << 4;
    const int cntb = wsI[WS_CNTB + b];
    if (base >= cntb) return;

    __shared__ short actX[16 * 80];    // [m][k<64], pitch 80 (16B-aligned rows)
    __shared__ short actA[16 * 264];   // [m][k<256], pitch 264
    __shared__ short actB[16 * 264];
    __shared__ int   recs[16];

    if (t < 16) {
        const int id = base + t;
        recs[t] = (id < cntb) ? wsI[WS_LIST + b*4096 + id] : -1;
    }
    __syncthreads();

    {   // gather x for 16 px -> bf16 LDS
        const int p = t & 15, cg = t >> 4;
        int hw = recs[p]; if (hw < 0) hw = recs[0];
        const float* xp = x + ((size_t)b * CCH) * (HH * WW) + hw;
        #pragma unroll
        for (int i = 0; i < 4; ++i) {
            const int c = cg*4 + i;
            actX[p*80 + c] = (short)f2bf(xp[(size_t)c * (HH * WW)]);
        }
    }
    __syncthreads();

    const int w = t >> 6, l = t & 63;
    const int lm = l & 15, lg = l >> 4;
    f32x4 acc[4];

    // ---- L1: words = x @ Wsem + bsem (no relu), K=64 -> actA
    #pragma unroll
    for (int nt = 0; nt < 4; ++nt) acc[nt] = f32x4{0.f, 0.f, 0.f, 0.f};
    #pragma unroll
    for (int kk = 0; kk < 2; ++kk) {
        const bf16x8 av = *reinterpret_cast<const bf16x8*>(&actX[lm*80 + kk*32 + lg*8]);
        #pragma unroll
        for (int nt = 0; nt < 4; ++nt) {
            const bf16x8 bv = *reinterpret_cast<const bf16x8*>(
                wb + WB_SEM + (size_t)((w*4 + nt)*2 + kk)*512 + l*8);
            acc[nt] = __builtin_amdgcn_mfma_f32_16x16x32_bf16(av, bv, acc[nt], 0, 0, 0);
        }
    }
    #pragma unroll
    for (int nt = 0; nt < 4; ++nt) {
        const int n = w*64 + nt*16 + lm;
        const float bias = bsem[n];
        #pragma unroll
        for (int r = 0; r < 4; ++r)
            actA[(lg*4 + r)*264 + n] = (short)f2bf(acc[nt][r] + bias);
    }
    __syncthreads();

    // ---- L2: h1 = relu(words @ W1 + b1), K=256 -> actB
    #pragma unroll
    for (int nt = 0; nt < 4; ++nt) acc[nt] = f32x4{0.f, 0.f, 0.f, 0.f};
    #pragma unroll
    for (int kk = 0; kk < 8; ++kk) {
        const bf16x8 av = *reinterpret_cast<const bf16x8*>(&actA[lm*264 + kk*32 + lg*8]);
        #pragma unroll
        for (int nt = 0; nt < 4; ++nt) {
            const bf16x8 bv = *reinterpret_cast<const bf16x8*>(
                wb + WB_W1 + (size_t)((w*4 + nt)*8 + kk)*512 + l*8);
            acc[nt] = __builtin_amdgcn_mfma_f32_16x16x32_bf16(av, bv, acc[nt], 0, 0, 0);
        }
    }
    #pragma unroll
    for (int nt = 0; nt < 4; ++nt) {
        const int n = w*64 + nt*16 + lm;
        const float bias = b1[n];
        #pragma unroll
        for (int r = 0; r < 4; ++r)
            actB[(lg*4 + r)*264 + n] = (short)f2bf(fmaxf(acc[nt][r] + bias, 0.f));
    }
    __syncthreads();

    // ---- L3: h2 = relu(h1 @ W2 + b2), K=256 -> actA
    #pragma unroll
    for (int nt = 0; nt < 4; ++nt) acc[nt] = f32x4{0.f, 0.f, 0.f, 0.f};
    #pragma unroll
    for (int kk = 0; kk < 8; ++kk) {
        const bf16x8 av = *reinterpret_cast<const bf16x8*>(&actB[lm*264 + kk*32 + lg*8]);
        #pragma unroll
        for (int nt = 0; nt < 4; ++nt) {
            const bf16x8 bv = *reinterpret_cast<const bf16x8*>(
                wb + WB_W2 + (size_t)((w*4 + nt)*8 + kk)*512 + l*8);
            acc[nt] = __builtin_amdgcn_mfma_f32_16x16x32_bf16(av, bv, acc[nt], 0, 0, 0);
        }
    }
    #pragma unroll
    for (int nt = 0; nt < 4; ++nt) {
        const int n = w*64 + nt*16 + lm;
        const float bias = b2[n];
        #pragma unroll
        for (int r = 0; r < 4; ++r)
            actA[(lg*4 + r)*264 + n] = (short)f2bf(fmaxf(acc[nt][r] + bias, 0.f));
    }
    __syncthreads();

    // ---- final: seg = h2 @ W3 + b3[0]; wave w handles px w*4..w*4+3
    const float w3v0 = W3[l], w3v1 = W3[l + 64], w3v2 = W3[l + 128], w3v3 = W3[l + 192];
    #pragma unroll
    for (int q = 0; q < 4; ++q) {
        const int p = w*4 + q;
        float v = bf2f((unsigned short)actA[p*264 + l])       * w3v0
                + bf2f((unsigned short)actA[p*264 + l + 64])  * w3v1
                + bf2f((unsigned short)actA[p*264 + l + 128]) * w3v2
                + bf2f((unsigned short)actA[p*264 + l + 192]) * w3v3;
        #pragma unroll
        for (int off = 32; off > 0; off >>= 1) v += __shfl_down(v, off);
        if (l == 0) {
            const int hw = recs[p];
            if (hw >= 0) out[SEG_OFF + hw*BB + b] = v + b3[0];
        }
    }
}

extern "C" void kernel_launch(void* const* d_in, const int* in_sizes, int n_in,
                              void* d_out, int out_size, void* d_ws, size_t ws_size,
                              hipStream_t stream) {
    const float* x    = (const float*)d_in[0];
    const float* rb   = (const float*)d_in[1];
    const float* Wsem = (const float*)d_in[2];
    const float* bsem = (const float*)d_in[3];
    const float* W1   = (const float*)d_in[4];
    const float* b1   = (const float*)d_in[5];
    const float* W2   = (const float*)d_in[6];
    const float* b2   = (const float*)d_in[7];
    const float* W3   = (const float*)d_in[8];
    const float* b3   = (const float*)d_in[9];
    float* out = (float*)d_out;
    int*   wsI = (int*)d_ws;
    float* wsF = (float*)d_ws;
    short* wb  = (short*)((char*)d_ws + WB_BYTE_OFF);

    k1_kernel<<<BB + 1 + 72, 256, 0, stream>>>(rb, Wsem, W1, W2, b1, b2, W3, b3,
                                               out, wsI, wsF, wb);
    k2_kernel<<<1280, 256, 0, stream>>>(x, bsem, b1, b2, W3, b3, wsI, wsF, wb, out);
}

// Round 5
// 99.993 us; speedup vs baseline: 2.0345x; 1.0568x over previous
//
#include <hip/hip_runtime.h>

typedef __attribute__((ext_vector_type(8))) short bf16x8;
typedef __attribute__((ext_vector_type(4))) float f32x4;

#define BB 4
#define CCH 64
#define HH 128
#define WW 128
#define DD 256
#define NBOX 100
#define MAXDET 10
#define TOPK 5

// out layout (floats): seg (HW,B,1), mask (B,H,W), kept (B,10,5), valid (B,10)
#define SEG_OFF   0
#define MASK_OFF  (BB * HH * WW)
#define KEPT_OFF  (MASK_OFF + BB * HH * WW)
#define VALID_OFF (KEPT_OFF + BB * MAXDET * 5)

// ws layout: int indices
#define WS_CNTB 0                     // 4 ints: per-batch worklist counts
#define WS_SEG0 8                     // 1 float
#define WS_BITS 16                    // 4096 ints: inside bits, layout [seg][batch]
#define WS_LIST (WS_BITS + 4096)      // 4*4096 ints: per-batch hw lists
// bf16 shuffled weights at byte offset 128K
#define WB_BYTE_OFF 131072
#define WB_SEM 0                      // 32 chunks  (K=64 : 4w*4nt*2kk)
#define WB_W1  (32 * 512)             // 128 chunks (K=256: 4w*4nt*8kk)
#define WB_W2  (160 * 512)            // 128 chunks

#define NMLP  256                     // persistent MLP blocks (64 per batch)
#define NFILL 64                      // seg0 fill blocks

__device__ __forceinline__ unsigned short f2bf(float f) {
    unsigned u = __float_as_uint(f);
    u = (u + 0x7FFFu + ((u >> 16) & 1u)) >> 16;
    return (unsigned short)u;
}
__device__ __forceinline__ float bf2f(unsigned short s) {
    return __uint_as_float(((unsigned)s) << 16);
}

// ---------------------------------------------------------------------------
// K1: blocks 0..3 = NMS (wave0) + rasterize (mask, bits, worklist) per batch;
//     block 4 = seg0 constant; blocks 5..76 = weight bf16 shuffle (4 chunks ea)
// ---------------------------------------------------------------------------
__global__ __launch_bounds__(256) void k1_kernel(
    const float* __restrict__ rb,
    const float* __restrict__ Wsem, const float* __restrict__ W1,
    const float* __restrict__ W2,
    const float* __restrict__ b1,   const float* __restrict__ b2,
    const float* __restrict__ W3,   const float* __restrict__ b3,
    float* __restrict__ out, int* __restrict__ wsI,
    float* __restrict__ wsF, short* __restrict__ wb)
{
    const int bid = blockIdx.x;
    const int t   = threadIdx.x;

    if (bid < BB) {
        __shared__ float lb[NBOX * 5];
        __shared__ int   rectsS[MAXDET * 4];
        __shared__ int   valdS[MAXDET];
        __shared__ int   sc[256];

        for (int k = t; k < NBOX * 5; k += 256) lb[k] = rb[bid * NBOX * 5 + k];
        __syncthreads();

        if (t < 64) {   // single-wave NMS, zero barriers inside
            const float b0x1 = lb[t*5], b0y1 = lb[t*5+1], b0x2 = lb[t*5+2],
                        b0y2 = lb[t*5+3], b0c = lb[t*5+4];
            const bool has1 = t < (NBOX - 64);
            const int  j1 = t + 64;
            float c1x1=0.f, c1y1=0.f, c1x2=0.f, c1y2=0.f, c1c=-INFINITY;
            if (has1) { c1x1=lb[j1*5]; c1y1=lb[j1*5+1]; c1x2=lb[j1*5+2];
                        c1y2=lb[j1*5+3]; c1c=lb[j1*5+4]; }
            const float a0 = fmaxf(b0x2-b0x1,0.f)*fmaxf(b0y2-b0y1,0.f);
            const float a1 = fmaxf(c1x2-c1x1,0.f)*fmaxf(c1y2-c1y1,0.f);

            unsigned long long bal = __ballot(b0c > 0.2f) | __ballot(has1 && (c1c > 0.2f));
            const bool use_thres = (bal != 0ULL);
            bool cand0 = use_thres ? (b0c > 0.2f) : true;
            bool cand1 = has1 && (use_thres ? (c1c > 0.2f) : true);

            for (int det = 0; det < MAXDET; ++det) {
                float v  = cand0 ? b0c : -INFINITY;
                int  idx = t;
                if (cand1 && c1c > v) { v = c1c; idx = j1; }
                for (int off = 1; off < 64; off <<= 1) {
                    float v2 = __shfl_xor(v, off);
                    int   i2 = __shfl_xor(idx, off);
                    if (v2 > v || (v2 == v && i2 < idx)) { v = v2; idx = i2; }
                }
                const bool has = (v > -INFINITY);
                const float sx1 = lb[idx*5], sy1 = lb[idx*5+1], sx2 = lb[idx*5+2],
                            sy2 = lb[idx*5+3], sc5 = lb[idx*5+4];
                if (has) {
                    const float sa = fmaxf(sx2-sx1,0.f)*fmaxf(sy2-sy1,0.f);
                    {
                        float lx=fmaxf(sx1,b0x1), ly=fmaxf(sy1,b0y1);
                        float rx=fminf(sx2,b0x2), ry=fminf(sy2,b0y2);
                        float inter=fmaxf(rx-lx,0.f)*fmaxf(ry-ly,0.f);
                        if (inter/(sa + a0 - inter + 1e-9f) > 0.4f) cand0 = false;
                    }
                    if (has1) {
                        float lx=fmaxf(sx1,c1x1), ly=fmaxf(sy1,c1y1);
                        float rx=fminf(sx2,c1x2), ry=fminf(sy2,c1y2);
                        float inter=fmaxf(rx-lx,0.f)*fmaxf(ry-ly,0.f);
                        if (inter/(sa + a1 - inter + 1e-9f) > 0.4f) cand1 = false;
                    }
                    if (idx == t)  cand0 = false;
                    if (idx == j1) cand1 = false;
                }
                if (t == 0) {
                    float* kp = out + KEPT_OFF + (bid*MAXDET + det)*5;
                    kp[0]=sx1; kp[1]=sy1; kp[2]=sx2; kp[3]=sy2; kp[4]=sc5;
                    const int vld = (has && (sx2-sx1 >= 1.f) && (sy2-sy1 >= 1.f) &&
                                     (use_thres || det < TOPK)) ? 1 : 0;
                    out[VALID_OFF + bid*MAXDET + det] = vld ? 1.f : 0.f;
                    int x1 = min(max((int)floorf(sx1+0.5f),0),WW);
                    int y1 = min(max((int)floorf(sy1+0.5f),0),HH);
                    int x2 = min(max((int)floorf(sx2+0.5f),0),WW);
                    int y2 = min(max((int)floorf(sy2+0.5f),0),HH);
                    rectsS[det*4]=x1; rectsS[det*4+1]=y1;
                    rectsS[det*4+2]=x2; rectsS[det*4+3]=y2;
                    valdS[det] = vld;
                }
            }
        }
        __syncthreads();

        // rasterize: thread t owns segments s = t*4 .. t*4+3 (64 consecutive px)
        int myBits[4];
        int n = 0;
        #pragma unroll
        for (int k = 0; k < 4; ++k) {
            const int s = t*4 + k;
            const int h = s >> 3, w0 = (s & 7) << 4;
            unsigned bits = 0;
            for (int d = 0; d < MAXDET; ++d) {
                if (valdS[d] && h >= rectsS[d*4+1] && h < rectsS[d*4+3]) {
                    const int lo = max(rectsS[d*4],   w0);
                    const int hi = min(rectsS[d*4+2], w0 + 16);
                    if (lo < hi) bits |= ((1u << (hi - w0)) - (1u << (lo - w0)));
                }
            }
            myBits[k] = (int)bits;
            n += __popc(bits);
            wsI[WS_BITS + s*4 + bid] = (int)bits;          // [seg][batch] layout
            float* mp = out + MASK_OFF + bid*(HH*WW) + s*16;
            #pragma unroll
            for (int q = 0; q < 4; ++q) {
                float4 v;
                v.x = ((bits >> (q*4+0)) & 1) ? 0.f : 1.f;
                v.y = ((bits >> (q*4+1)) & 1) ? 0.f : 1.f;
                v.z = ((bits >> (q*4+2)) & 1) ? 0.f : 1.f;
                v.w = ((bits >> (q*4+3)) & 1) ? 0.f : 1.f;
                *reinterpret_cast<float4*>(mp + q*4) = v;
            }
        }
        sc[t] = n;
        __syncthreads();
        for (int off = 1; off < 256; off <<= 1) {
            const int v = (t >= off) ? sc[t - off] : 0;
            __syncthreads();
            sc[t] += v;
            __syncthreads();
        }
        if (t == 255) wsI[WS_CNTB + bid] = sc[255];
        int pos = sc[t] - n;
        #pragma unroll
        for (int k = 0; k < 4; ++k) {
            unsigned bitsr = (unsigned)myBits[k];
            const int s = t*4 + k;
            while (bitsr) {
                const int bp = __ffs(bitsr) - 1;
                bitsr &= bitsr - 1;
                wsI[WS_LIST + bid*4096 + pos++] = s*16 + bp;
            }
        }
    } else if (bid == BB) {
        // seg0 = MLP(0); unroll so W2 column loads pipeline
        __shared__ float h1s[DD];
        __shared__ float red[DD];
        h1s[t] = fmaxf(b1[t], 0.f);
        __syncthreads();
        float acc = b2[t];
        #pragma unroll 8
        for (int i = 0; i < DD; ++i) acc = fmaf(h1s[i], W2[i*DD + t], acc);
        red[t] = fmaxf(acc, 0.f) * W3[t];
        __syncthreads();
        for (int off = 128; off > 0; off >>= 1) {
            if (t < off) red[t] += red[t + off];
            __syncthreads();
        }
        if (t == 0) wsF[WS_SEG0] = red[0] + b3[0];
    } else {
        // weight shuffle into B-fragment chunk order:
        // chunk[l*8+j] = W[kk*32 + (l>>4)*8 + j][w*64 + nt*16 + (l&15)]
        const int g = (bid - BB - 1) * 4 + (t >> 6);   // 0..287
        const int l = t & 63;
        const float* src; int KK32, cp, sbase;
        if (g < 32)       { src = Wsem; KK32 = 2; cp = g;       sbase = WB_SEM; }
        else if (g < 160) { src = W1;   KK32 = 8; cp = g - 32;  sbase = WB_W1; }
        else              { src = W2;   KK32 = 8; cp = g - 160; sbase = WB_W2; }
        const int wq  = cp / (4 * KK32);
        const int rem = cp % (4 * KK32);
        const int nt = rem / KK32, kk = rem % KK32;
        const int k0 = kk*32 + (l >> 4)*8;
        const int nn = wq*64 + nt*16 + (l & 15);
        unsigned short h[8];
        #pragma unroll
        for (int j = 0; j < 8; ++j) h[j] = f2bf(src[(size_t)(k0 + j) * DD + nn]);
        int4 v;
        v.x = (int)((unsigned)h[0] | ((unsigned)h[1] << 16));
        v.y = (int)((unsigned)h[2] | ((unsigned)h[3] << 16));
        v.z = (int)((unsigned)h[4] | ((unsigned)h[5] << 16));
        v.w = (int)((unsigned)h[6] | ((unsigned)h[7] << 16));
        *reinterpret_cast<int4*>(wb + sbase + (size_t)cp*512 + l*8) = v;
    }
}

// ---------------------------------------------------------------------------
// K2: blocks [0,NMLP) = persistent MFMA MLP (64 blocks/batch, stride over
//     16-px chunks); blocks [NMLP,NMLP+NFILL) = float4 seg0 fill (bit-guarded)
// ---------------------------------------------------------------------------
__global__ __launch_bounds__(256) void k2_kernel(
    const float* __restrict__ x,
    const float* __restrict__ bsem, const float* __restrict__ b1,
    const float* __restrict__ b2,   const float* __restrict__ W3,
    const float* __restrict__ b3,
    const int* __restrict__ wsI, const float* __restrict__ wsF,
    const short* __restrict__ wb, float* __restrict__ out)
{
    const int bi = blockIdx.x;
    const int t  = threadIdx.x;

    if (bi >= NMLP) {
        // fill: thread owns one hw, all 4 batches; mostly one float4 store
        const int hw  = (bi - NMLP) * 256 + t;          // 64*256 = 16384
        const int s   = hw >> 4, bit = hw & 15;
        const int4 bw = *reinterpret_cast<const int4*>(wsI + WS_BITS + s*4);
        const float s0 = wsF[WS_SEG0];
        const unsigned i0 = (((unsigned)bw.x) >> bit) & 1u;
        const unsigned i1 = (((unsigned)bw.y) >> bit) & 1u;
        const unsigned i2 = (((unsigned)bw.z) >> bit) & 1u;
        const unsigned i3 = (((unsigned)bw.w) >> bit) & 1u;
        float* op = out + SEG_OFF + hw * 4;
        if (!(i0 | i1 | i2 | i3)) {
            float4 v; v.x = s0; v.y = s0; v.z = s0; v.w = s0;
            *reinterpret_cast<float4*>(op) = v;
        } else {
            if (!i0) op[0] = s0;
            if (!i1) op[1] = s0;
            if (!i2) op[2] = s0;
            if (!i3) op[3] = s0;
        }
        return;
    }

    const int b    = bi >> 6;          // 64 blocks per batch
    const int blk  = bi & 63;
    const int cntb = wsI[WS_CNTB + b];

    __shared__ short actX[16 * 80];    // [m][k<64], pitch 80
    __shared__ short actA[16 * 264];   // [m][k<256], pitch 264
    __shared__ short actB[16 * 264];
    __shared__ int   recs[16];

    const int w = t >> 6, l = t & 63;
    const int lm = l & 15, lg = l >> 4;

    for (int base = blk * 16; base < cntb; base += NMLP / BB * 16) {
        __syncthreads();               // protect recs/LDS reuse across chunks
        if (t < 16) {
            const int id = base + t;
            recs[t] = (id < cntb) ? wsI[WS_LIST + b*4096 + id] : -1;
        }
        __syncthreads();

        {   // gather x for 16 px -> bf16 LDS
            const int p = t & 15, cg = t >> 4;
            int hw = recs[p]; if (hw < 0) hw = recs[0];
            const float* xp = x + ((size_t)b * CCH) * (HH * WW) + hw;
            #pragma unroll
            for (int i = 0; i < 4; ++i) {
                const int c = cg*4 + i;
                actX[p*80 + c] = (short)f2bf(xp[(size_t)c * (HH * WW)]);
            }
        }
        __syncthreads();

        f32x4 acc[4];

        // ---- L1: words = x @ Wsem + bsem (no relu), K=64 -> actA
        #pragma unroll
        for (int nt = 0; nt < 4; ++nt) acc[nt] = f32x4{0.f, 0.f, 0.f, 0.f};
        #pragma unroll
        for (int kk = 0; kk < 2; ++kk) {
            const bf16x8 av = *reinterpret_cast<const bf16x8*>(&actX[lm*80 + kk*32 + lg*8]);
            #pragma unroll
            for (int nt = 0; nt < 4; ++nt) {
                const bf16x8 bv = *reinterpret_cast<const bf16x8*>(
                    wb + WB_SEM + (size_t)((w*4 + nt)*2 + kk)*512 + l*8);
                acc[nt] = __builtin_amdgcn_mfma_f32_16x16x32_bf16(av, bv, acc[nt], 0, 0, 0);
            }
        }
        #pragma unroll
        for (int nt = 0; nt < 4; ++nt) {
            const int n = w*64 + nt*16 + lm;
            const float bias = bsem[n];
            #pragma unroll
            for (int r = 0; r < 4; ++r)
                actA[(lg*4 + r)*264 + n] = (short)f2bf(acc[nt][r] + bias);
        }
        __syncthreads();

        // ---- L2: h1 = relu(words @ W1 + b1), K=256 -> actB
        #pragma unroll
        for (int nt = 0; nt < 4; ++nt) acc[nt] = f32x4{0.f, 0.f, 0.f, 0.f};
        #pragma unroll
        for (int kk = 0; kk < 8; ++kk) {
            const bf16x8 av = *reinterpret_cast<const bf16x8*>(&actA[lm*264 + kk*32 + lg*8]);
            #pragma unroll
            for (int nt = 0; nt < 4; ++nt) {
                const bf16x8 bv = *reinterpret_cast<const bf16x8*>(
                    wb + WB_W1 + (size_t)((w*4 + nt)*8 + kk)*512 + l*8);
                acc[nt] = __builtin_amdgcn_mfma_f32_16x16x32_bf16(av, bv, acc[nt], 0, 0, 0);
            }
        }
        #pragma unroll
        for (int nt = 0; nt < 4; ++nt) {
            const int n = w*64 + nt*16 + lm;
            const float bias = b1[n];
            #pragma unroll
            for (int r = 0; r < 4; ++r)
                actB[(lg*4 + r)*264 + n] = (short)f2bf(fmaxf(acc[nt][r] + bias, 0.f));
        }
        __syncthreads();

        // ---- L3: h2 = relu(h1 @ W2 + b2), K=256 -> actA
        #pragma unroll
        for (int nt = 0; nt < 4; ++nt) acc[nt] = f32x4{0.f, 0.f, 0.f, 0.f};
        #pragma unroll
        for (int kk = 0; kk < 8; ++kk) {
            const bf16x8 av = *reinterpret_cast<const bf16x8*>(&actB[lm*264 + kk*32 + lg*8]);
            #pragma unroll
            for (int nt = 0; nt < 4; ++nt) {
                const bf16x8 bv = *reinterpret_cast<const bf16x8*>(
                    wb + WB_W2 + (size_t)((w*4 + nt)*8 + kk)*512 + l*8);
                acc[nt] = __builtin_amdgcn_mfma_f32_16x16x32_bf16(av, bv, acc[nt], 0, 0, 0);
            }
        }
        #pragma unroll
        for (int nt = 0; nt < 4; ++nt) {
            const int n = w*64 + nt*16 + lm;
            const float bias = b2[n];
            #pragma unroll
            for (int r = 0; r < 4; ++r)
                actA[(lg*4 + r)*264 + n] = (short)f2bf(fmaxf(acc[nt][r] + bias, 0.f));
        }
        __syncthreads();

        // ---- final: seg = h2 @ W3 + b3[0]; wave w handles px w*4..w*4+3
        const float w3v0 = W3[l], w3v1 = W3[l + 64], w3v2 = W3[l + 128], w3v3 = W3[l + 192];
        #pragma unroll
        for (int q = 0; q < 4; ++q) {
            const int p = w*4 + q;
            float v = bf2f((unsigned short)actA[p*264 + l])       * w3v0
                    + bf2f((unsigned short)actA[p*264 + l + 64])  * w3v1
                    + bf2f((unsigned short)actA[p*264 + l + 128]) * w3v2
                    + bf2f((unsigned short)actA[p*264 + l + 192]) * w3v3;
            #pragma unroll
            for (int off = 32; off > 0; off >>= 1) v += __shfl_down(v, off);
            if (l == 0) {
                const int hw = recs[p];
                if (hw >= 0) out[SEG_OFF + hw*4 + b] = v + b3[0];
            }
        }
    }
}

extern "C" void kernel_launch(void* const* d_in, const int* in_sizes, int n_in,
                              void* d_out, int out_size, void* d_ws, size_t ws_size,
                              hipStream_t stream) {
    const float* x    = (const float*)d_in[0];
    const float* rb   = (const float*)d_in[1];
    const float* Wsem = (const float*)d_in[2];
    const float* bsem = (const float*)d_in[3];
    const float* W1   = (const float*)d_in[4];
    const float* b1   = (const float*)d_in[5];
    const float* W2   = (const float*)d_in[6];
    const float* b2   = (const float*)d_in[7];
    const float* W3   = (const float*)d_in[8];
    const float* b3   = (const float*)d_in[9];
    float* out = (float*)d_out;
    int*   wsI = (int*)d_ws;
    float* wsF = (float*)d_ws;
    short* wb  = (short*)((char*)d_ws + WB_BYTE_OFF);

    k1_kernel<<<BB + 1 + 72, 256, 0, stream>>>(rb, Wsem, W1, W2, b1, b2, W3, b3,
                                               out, wsI, wsF, wb);
    k2_kernel<<<NMLP + NFILL, 256, 0, stream>>>(x, bsem, b1, b2, W3, b3,
                                                wsI, wsF, wb, out);
}